// Round 11
// baseline (2077.695 us; speedup 1.0000x reference)
//
#include <hip/hip_runtime.h>
#include <cstdint>

#define B_    16
#define L_    512
#define D_    768
#define DFF_  3072
#define DLLM_ 4096
#define E_    8

typedef unsigned short ushort_t;
typedef __attribute__((ext_vector_type(4))) float accfrag_t;
typedef __attribute__((ext_vector_type(8))) short bfrag_t;

typedef __attribute__((address_space(3))) uint32_t lds_u32;
typedef __attribute__((address_space(1))) uint32_t glb_u32;

__device__ inline void gload16(const void* g, void* l) {
  __builtin_amdgcn_global_load_lds((const glb_u32*)(uintptr_t)g,
                                   (lds_u32*)(uint32_t)(uintptr_t)l, 16, 0, 0);
}

__device__ inline ushort_t f2bf(float f) {
  uint32_t u = __float_as_uint(f);
  return (ushort_t)((u + 0x7FFFu + ((u >> 16) & 1u)) >> 16);  // RNE
}
__device__ inline float bf2f(ushort_t v) { return __uint_as_float(((uint32_t)v) << 16); }

#define MFMA16(a, b, c) __builtin_amdgcn_mfma_f32_16x16x32_bf16(a, b, c, 0, 0, 0)

// ---------------------------------------------------------------------------
// m97-class 128x128 tile GEMM, BK=64, 4 waves (2Mx2N), 256 threads,
// single 32KB LDS buffer, 2 barriers/K-step, FIVE blocks/CU
// (launch_bounds(256,5): 5 x 32KB = 160KB LDS, 76 VGPR x 20 waves fits).
// r9 post-mortem: at 3 blocks/CU the kernel is latency/outstanding-bound
// (17 B/cyc/CU delivered, not HBM/L2 BW); more resident waves = more
// outstanding gload16 = higher delivery.  Occupancy is the lever, schedule
// sophistication at 1 block/CU repeatedly failed (r5/6/7/10).
// Swizzle: 16B chunk lc of row r stored at lc ^ (r&7), folded into the
// pre-swizzled GLOBAL source + ds_read offsets.  Measured 0 conflicts.
// ---------------------------------------------------------------------------
template <int KT>  // KT = K/64
__device__ __forceinline__ void gemm_body(const char* gA, const char* gB,
                                          char* sm, accfrag_t acc[4][4]) {
  const int tid = threadIdx.x;
  const int lane = tid & 63;
  const int w = tid >> 6, wm = w >> 1, wn = w & 1;
  const int LDB = KT * 128;  // row stride bytes (= K*2)

  const int R0 = tid >> 3;
  const char* srcA = gA + (size_t)R0 * LDB + ((((tid & 7) ^ (R0 & 7)) << 4));
  const char* srcB = gB + (size_t)R0 * LDB + ((((tid & 7) ^ (R0 & 7)) << 4));
  const int dl = tid * 16;

  const int l15 = lane & 15, l7 = lane & 7, lhi = lane >> 4;
  const int a0 = (wm * 64 + l15) * 128 + ((lhi ^ l7) << 4);
  const int a1 = (wm * 64 + l15) * 128 + (((4 + lhi) ^ l7) << 4);
  const int b0 = 16384 + (wn * 64 + l15) * 128 + ((lhi ^ l7) << 4);
  const int b1 = 16384 + (wn * 64 + l15) * 128 + (((4 + lhi) ^ l7) << 4);

#pragma unroll 1
  for (int t = 0; t < KT; ++t) {
    const size_t ko = (size_t)t * 128;
#pragma unroll
    for (int j = 0; j < 4; ++j)
      gload16(srcA + (size_t)j * 32 * LDB + ko, sm + j * 4096 + dl);
#pragma unroll
    for (int j = 0; j < 4; ++j)
      gload16(srcB + (size_t)j * 32 * LDB + ko, sm + 16384 + j * 4096 + dl);
    __syncthreads();
    bfrag_t af0[4], af1[4], bf0[4], bf1[4];
#pragma unroll
    for (int nf = 0; nf < 4; ++nf) {
      bf0[nf] = *(const bfrag_t*)(sm + b0 + nf * 2048);
      bf1[nf] = *(const bfrag_t*)(sm + b1 + nf * 2048);
    }
#pragma unroll
    for (int mf = 0; mf < 4; ++mf) {
      af0[mf] = *(const bfrag_t*)(sm + a0 + mf * 2048);
      af1[mf] = *(const bfrag_t*)(sm + a1 + mf * 2048);
    }
    __builtin_amdgcn_s_setprio(1);
#pragma unroll
    for (int mf = 0; mf < 4; ++mf)
#pragma unroll
      for (int nf = 0; nf < 4; ++nf) {
        acc[mf][nf] = MFMA16(af0[mf], bf0[nf], acc[mf][nf]);
        acc[mf][nf] = MFMA16(af1[mf], bf1[nf], acc[mf][nf]);
      }
    __builtin_amdgcn_s_setprio(0);
    __syncthreads();
  }
}

// XCD job-clustering remap (bijective when JP%8==0): physical flat id f runs
// on XCD f%8 [m09]; map so ALL blocks of a job share one XCD -> its L2 holds
// that job's weight/x panels instead of 8 jobs' worth.
__device__ inline void job_tile(int f, int tilesPerJob, int jp_count,
                                int& jobIdx, int& t) {
  if ((jp_count & 7) == 0) {
    const int xcd = f & 7, slot = f >> 3;
    jobIdx = xcd + 8 * (slot / tilesPerJob);
    t = slot % tilesPerJob;
  } else {
    jobIdx = f / tilesPerJob;
    t = f % tilesPerJob;
  }
}

// ---------------------------------------------------------------------------
// GEMM1: h = GELU_tanh(x @ W1 + b1), bf16 out [JP][512][3072]
// 1D grid 96*JP; tile t: mt = t/24 (A-panel-major), nt = t%24.
// Direct global_store_short epilogue (no LDS round-trip, no barriers).
// ---------------------------------------------------------------------------
__global__ __launch_bounds__(256, 5)
void gemm1_k(const ushort_t* __restrict__ xb, const ushort_t* __restrict__ w1t,
             const float* __restrict__ e_b1, const float* __restrict__ g_b1,
             const int* __restrict__ tidx, ushort_t* __restrict__ h_out,
             int job0, int jp_count) {
  __shared__ char sm[32768];
  int jp, t;
  job_tile(blockIdx.x, 96, jp_count, jp, t);
  const int mt = t / 24, nt = t % 24;
  const int job = job0 + jp;
  const int b = job / 3, s = job - b * 3;
  const int e = (s < 2) ? tidx[b * 2 + s] : E_;
  const char* gA = (const char*)(xb + ((size_t)b * L_ + mt * 128) * D_);
  const char* gB = (const char*)(w1t + ((size_t)e * DFF_ + nt * 128) * D_);
  accfrag_t acc[4][4] = {};
  gemm_body<12>(gA, gB, sm, acc);

  const float* b1 = (s < 2) ? (e_b1 + (size_t)e * DFF_) : g_b1;
  const int lane = threadIdx.x & 63, w = threadIdx.x >> 6;
  const int wm = w >> 1, wn = w & 1;
  const int row0 = mt * 128 + wm * 64 + ((lane >> 4) << 2);
  const int col0 = nt * 128 + wn * 64 + (lane & 15);
  float bias[4];
#pragma unroll
  for (int nf = 0; nf < 4; ++nf) bias[nf] = b1[col0 + nf * 16];
  ushort_t* hp = h_out + (size_t)jp * L_ * DFF_ + (size_t)row0 * DFF_ + col0;
#pragma unroll
  for (int mf = 0; mf < 4; ++mf)
#pragma unroll
    for (int r = 0; r < 4; ++r) {
      ushort_t* hr_ = hp + (size_t)(mf * 16 + r) * DFF_;
#pragma unroll
      for (int nf = 0; nf < 4; ++nf) {
        float v = acc[mf][nf][r] + bias[nf];
        float u = 0.7978845608028654f * (v + 0.044715f * v * v * v);
        float th = 1.0f - 2.0f / (1.0f + __expf(2.0f * u));  // tanh(u)
        hr_[nf * 16] = f2bf(0.5f * v * (1.0f + th));
      }
    }
}

// ---------------------------------------------------------------------------
// GEMM2: o = h @ W2 + b2 + x.  s<2 -> bf16 slot buffer; s==2 -> f32 d_out.
// 1D grid 24*JP; tile t: mt = t/6 (A-panel-major), nt = t%6.
// ---------------------------------------------------------------------------
__global__ __launch_bounds__(256, 5)
void gemm2_k(const ushort_t* __restrict__ h_in, const ushort_t* __restrict__ w2t,
             const float* __restrict__ e_b2, const float* __restrict__ g_b2,
             const float* __restrict__ x_f, const int* __restrict__ tidx,
             ushort_t* __restrict__ slot_o, float* __restrict__ outp,
             int job0, int jp_count) {
  __shared__ char sm[32768];
  int jp, t;
  job_tile(blockIdx.x, 24, jp_count, jp, t);
  const int mt = t / 6, nt = t % 6;
  const int job = job0 + jp;
  const int b = job / 3, s = job - b * 3;
  const int e = (s < 2) ? tidx[b * 2 + s] : E_;
  const char* gA = (const char*)(h_in + ((size_t)jp * L_ + mt * 128) * DFF_);
  const char* gB = (const char*)(w2t + ((size_t)e * D_ + nt * 128) * DFF_);
  accfrag_t acc[4][4] = {};
  gemm_body<48>(gA, gB, sm, acc);

  const float* b2 = (s < 2) ? (e_b2 + (size_t)e * D_) : g_b2;
  const int lane = threadIdx.x & 63, w = threadIdx.x >> 6;
  const int wm = w >> 1, wn = w & 1;
  const int row0 = mt * 128 + wm * 64 + ((lane >> 4) << 2);
  const int col0 = nt * 128 + wn * 64 + (lane & 15);
  float bias[4];
#pragma unroll
  for (int nf = 0; nf < 4; ++nf) bias[nf] = b2[col0 + nf * 16];
#pragma unroll
  for (int mf = 0; mf < 4; ++mf)
#pragma unroll
    for (int r = 0; r < 4; ++r) {
      const int row = row0 + mf * 16 + r;
      const float* xr = x_f + ((size_t)b * L_ + row) * D_ + col0;
#pragma unroll
      for (int nf = 0; nf < 4; ++nf) {
        float v = acc[mf][nf][r] + bias[nf] + xr[nf * 16];
        if (s < 2)
          slot_o[(((size_t)b * 2 + s) * L_ + row) * D_ + col0 + nf * 16] = f2bf(v);
        else
          outp[((size_t)b * L_ + row) * D_ + col0 + nf * 16] = v;
      }
    }
}

// ---------------------------------------------------------------------------
// Weight transpose + f32->bf16: src [R][C] f32 (8 experts + general)
// -> dst [9][C][R] bf16.  64x64 tiles; out[c][r] = tile[r][c].
// ---------------------------------------------------------------------------
__global__ __launch_bounds__(256)
void transpose_cvt_k(const float* __restrict__ srcE, const float* __restrict__ srcG,
                     ushort_t* __restrict__ dst, int R, int C) {
  const int z = blockIdx.z;
  const float* src = (z < 8) ? (srcE + (size_t)z * R * C) : srcG;
  ushort_t* out = dst + (size_t)z * R * C;
  __shared__ float tile[64][65];
  const int c0 = blockIdx.x * 64, r0 = blockIdx.y * 64;
  const int t = threadIdx.x;
  const int rr = t >> 4, cc = (t & 15) * 4;
#pragma unroll
  for (int i = 0; i < 4; ++i) {
    const float4 v = *(const float4*)(src + (size_t)(r0 + rr + i * 16) * C + c0 + cc);
    tile[rr + i * 16][cc] = v.x; tile[rr + i * 16][cc + 1] = v.y;
    tile[rr + i * 16][cc + 2] = v.z; tile[rr + i * 16][cc + 3] = v.w;
  }
  __syncthreads();
  const int c = t >> 2, r8 = (t & 3) * 16;
#pragma unroll
  for (int j = 0; j < 2; ++j) {
    ushort_t u[8];
#pragma unroll
    for (int k = 0; k < 8; ++k) u[k] = f2bf(tile[r8 + j * 8 + k][c]);
    *(uint4*)(out + (size_t)(c0 + c) * R + r0 + r8 + j * 8) = *(const uint4*)u;
  }
}

__global__ void cvt_x_k(const float* __restrict__ in, ushort_t* __restrict__ out) {
  const int i = (blockIdx.x * 256 + threadIdx.x) * 4;
  const float4 v = *(const float4*)(in + i);
  uint2 u;
  u.x = (uint32_t)f2bf(v.x) | ((uint32_t)f2bf(v.y) << 16);
  u.y = (uint32_t)f2bf(v.z) | ((uint32_t)f2bf(v.w) << 16);
  *(uint2*)(out + i) = u;
}

// ---------------------------------------------------------------------------
// Router: h = relu(emb @ We + cyc*Wc + b)
// ---------------------------------------------------------------------------
__global__ __launch_bounds__(256)
void router_partial_k(const float* __restrict__ emb, const float* __restrict__ We,
                      float* __restrict__ rp) {
  const int nt = blockIdx.x, kb = blockIdx.y;  // 12 x 16
  const int tid = threadIdx.x;
  __shared__ float semb[B_][256];
  const int k0 = kb * 256;
#pragma unroll
  for (int r = 0; r < B_; ++r) semb[r][tid] = emb[(size_t)r * DLLM_ + k0 + tid];
  __syncthreads();
  const int f = nt * 256 + tid;
  float acc[B_] = {};
  for (int k = 0; k < 256; ++k) {
    const float wv = We[(size_t)(k0 + k) * DFF_ + f];
#pragma unroll
    for (int j = 0; j < B_; ++j) acc[j] += semb[j][k] * wv;
  }
#pragma unroll
  for (int j = 0; j < B_; ++j)
    rp[((size_t)kb * B_ + j) * DFF_ + f] = acc[j];
}

__global__ void router_reduce_k(const float* __restrict__ rp, const float* __restrict__ cyc,
                                const float* __restrict__ Wc, const float* __restrict__ gb,
                                float* __restrict__ hr) {
  const int g = blockIdx.x * 256 + threadIdx.x;
  const int b = g / DFF_, f = g - b * DFF_;
  float s = 0.0f;
#pragma unroll
  for (int kb = 0; kb < 16; ++kb)
    s += rp[((size_t)kb * B_ + b) * DFF_ + f];
  s += cyc[b] * Wc[f] + gb[f];
  hr[(size_t)b * DFF_ + f] = fmaxf(s, 0.0f);
}

__global__ void router_final_k(const float* __restrict__ hr, const float* __restrict__ Wo,
                               const float* __restrict__ bo, int* __restrict__ tidx,
                               float* __restrict__ gates) {
  const int b = blockIdx.x, tid = threadIdx.x;
  float acc[E_] = {};
  for (int f = tid; f < DFF_; f += 256) {
    const float hv = hr[(size_t)b * DFF_ + f];
#pragma unroll
    for (int o = 0; o < E_; ++o) acc[o] += hv * Wo[(size_t)f * E_ + o];
  }
  __shared__ float lred[E_][4];
#pragma unroll
  for (int o = 0; o < E_; ++o) {
    float v = acc[o];
#pragma unroll
    for (int off = 32; off > 0; off >>= 1) v += __shfl_down(v, off, 64);
    if ((tid & 63) == 0) lred[o][tid >> 6] = v;
  }
  __syncthreads();
  if (tid == 0) {
    float lg[E_];
    float mx = -1e30f;
    for (int o = 0; o < E_; ++o) {
      lg[o] = lred[o][0] + lred[o][1] + lred[o][2] + lred[o][3] + bo[o];
      mx = fmaxf(mx, lg[o]);
    }
    int i1 = 0;
    for (int o = 1; o < E_; ++o) if (lg[o] > lg[i1]) i1 = o;
    int i2 = (i1 == 0) ? 1 : 0;
    for (int o = 0; o < E_; ++o) if (o != i1 && lg[o] > lg[i2]) i2 = o;
    float p[E_], sum = 0.0f;
    for (int o = 0; o < E_; ++o) { p[o] = __expf(lg[o] - mx); sum += p[o]; }
    const float p1 = p[i1] / sum, p2 = p[i2] / sum;
    const float den = p1 + p2 + 1e-9f;
    tidx[b * 2] = i1; tidx[b * 2 + 1] = i2;
    gates[b * 2] = p1 / den; gates[b * 2 + 1] = p2 / den;
  }
}

// ---------------------------------------------------------------------------
// Final: 3-way LayerNorm + gating + bf16 cast of combined; f32 output.
// ---------------------------------------------------------------------------
__global__ __launch_bounds__(256)
void final_ln_k(float* __restrict__ outp, const ushort_t* __restrict__ so,
                const float* __restrict__ gates, const int* __restrict__ tidx,
                const float* __restrict__ e_gam, const float* __restrict__ e_bet,
                const float* __restrict__ g_gam, const float* __restrict__ g_bet) {
  const int row = blockIdx.x;
  const int b = row >> 9, l = row & 511;
  const int tid = threadIdx.x;
  __shared__ float red4[4];
  float* gr = outp + (size_t)row * D_;
  const ushort_t* s0 = so + (((size_t)b * 2 + 0) * L_ + l) * D_;
  const ushort_t* s1 = so + (((size_t)b * 2 + 1) * L_ + l) * D_;
  float a0[3], a1[3], a2[3];
#pragma unroll
  for (int j = 0; j < 3; ++j) {
    const int d = tid + j * 256;
    a0[j] = gr[d];
    a1[j] = bf2f(s0[d]);
    a2[j] = bf2f(s1[d]);
  }
  auto bsum = [&](float v) -> float {
#pragma unroll
    for (int o = 32; o > 0; o >>= 1) v += __shfl_down(v, o, 64);
    if ((tid & 63) == 0) red4[tid >> 6] = v;
    __syncthreads();
    const float r = red4[0] + red4[1] + red4[2] + red4[3];
    __syncthreads();
    return r;
  };
  const float sg = bsum(a0[0] + a0[1] + a0[2]);
  const float qg = bsum(a0[0] * a0[0] + a0[1] * a0[1] + a0[2] * a0[2]);
  const float s0s = bsum(a1[0] + a1[1] + a1[2]);
  const float q0s = bsum(a1[0] * a1[0] + a1[1] * a1[1] + a1[2] * a1[2]);
  const float s1s = bsum(a2[0] + a2[1] + a2[2]);
  const float q1s = bsum(a2[0] * a2[0] + a2[1] * a2[1] + a2[2] * a2[2]);
  const float inv = 1.0f / 768.0f;
  const float mug = sg * inv, rg = rsqrtf(qg * inv - mug * mug + 1e-5f);
  const float mu0 = s0s * inv, r0 = rsqrtf(q0s * inv - mu0 * mu0 + 1e-5f);
  const float mu1 = s1s * inv, r1 = rsqrtf(q1s * inv - mu1 * mu1 + 1e-5f);
  const int e0 = tidx[b * 2], e1 = tidx[b * 2 + 1];
  const float g0 = gates[b * 2], g1 = gates[b * 2 + 1];
#pragma unroll
  for (int j = 0; j < 3; ++j) {
    const int d = tid + j * 256;
    const float lng = (a0[j] - mug) * rg * g_gam[d] + g_bet[d];
    const float ln0 = (a1[j] - mu0) * r0 * e_gam[(size_t)e0 * D_ + d] + e_bet[(size_t)e0 * D_ + d];
    const float ln1 = (a2[j] - mu1) * r1 * e_gam[(size_t)e1 * D_ + d] + e_bet[(size_t)e1 * D_ + d];
    const float comb = g0 * ln0 + g1 * ln1;
    gr[d] = lng + bf2f(f2bf(comb));
  }
}

// ---------------------------------------------------------------------------
extern "C" void kernel_launch(void* const* d_in, const int* in_sizes, int n_in,
                              void* d_out, int out_size, void* d_ws, size_t ws_size,
                              hipStream_t stream) {
  const float* x_f  = (const float*)d_in[0];
  const float* cyc  = (const float*)d_in[1];
  const float* emb  = (const float*)d_in[2];
  const float* We   = (const float*)d_in[3];
  const float* Wc   = (const float*)d_in[4];
  const float* gb   = (const float*)d_in[5];
  const float* Wo   = (const float*)d_in[6];
  const float* bo   = (const float*)d_in[7];
  const float* e_w1 = (const float*)d_in[8];
  const float* e_b1 = (const float*)d_in[9];
  const float* e_w2 = (const float*)d_in[10];
  const float* e_b2 = (const float*)d_in[11];
  const float* e_gam = (const float*)d_in[12];
  const float* e_bet = (const float*)d_in[13];
  const float* g_w1 = (const float*)d_in[14];
  const float* g_b1 = (const float*)d_in[15];
  const float* g_w2 = (const float*)d_in[16];
  const float* g_b2 = (const float*)d_in[17];
  const float* g_gam = (const float*)d_in[18];
  const float* g_bet = (const float*)d_in[19];
  float* outp = (float*)d_out;
  char* ws = (char*)d_ws;

  size_t off = 0;
  auto alloc = [&](size_t bytes) { size_t o = off; off = (off + bytes + 255) & ~(size_t)255; return o; };
  const size_t o_idx  = alloc(32 * 4);
  const size_t o_gate = alloc(32 * 4);
  const size_t o_hr   = alloc((size_t)B_ * DFF_ * 4);
  const size_t o_rp   = alloc((size_t)16 * B_ * DFF_ * 4);
  const size_t o_xb   = alloc((size_t)B_ * L_ * D_ * 2);
  const size_t o_w1t  = alloc((size_t)9 * DFF_ * D_ * 2);
  const size_t o_w2t  = alloc((size_t)9 * D_ * DFF_ * 2);
  const size_t o_so   = alloc((size_t)B_ * 2 * L_ * D_ * 2);
  const size_t o_h    = off;

  int JP = 1;
  const int divs[10] = {48, 24, 16, 12, 8, 6, 4, 3, 2, 1};
  for (int k = 0; k < 10; ++k) {
    if (o_h + (size_t)divs[k] * L_ * DFF_ * 2 <= ws_size) { JP = divs[k]; break; }
  }

  ushort_t* xb    = (ushort_t*)(ws + o_xb);
  ushort_t* w1t   = (ushort_t*)(ws + o_w1t);
  ushort_t* w2t   = (ushort_t*)(ws + o_w2t);
  ushort_t* so    = (ushort_t*)(ws + o_so);
  ushort_t* h_ws  = (ushort_t*)(ws + o_h);
  int*      tidx  = (int*)(ws + o_idx);
  float*    gates = (float*)(ws + o_gate);
  float*    hr    = (float*)(ws + o_hr);
  float*    rp    = (float*)(ws + o_rp);

  cvt_x_k<<<dim3((B_ * L_ * D_) / 1024), dim3(256), 0, stream>>>(x_f, xb);
  transpose_cvt_k<<<dim3(DFF_ / 64, D_ / 64, 9), dim3(256), 0, stream>>>(e_w1, g_w1, w1t, D_, DFF_);
  transpose_cvt_k<<<dim3(D_ / 64, DFF_ / 64, 9), dim3(256), 0, stream>>>(e_w2, g_w2, w2t, DFF_, D_);
  router_partial_k<<<dim3(12, 16), dim3(256), 0, stream>>>(emb, We, rp);
  router_reduce_k<<<dim3(192), dim3(256), 0, stream>>>(rp, cyc, Wc, gb, hr);
  router_final_k<<<dim3(16), dim3(256), 0, stream>>>(hr, Wo, bo, tidx, gates);

  const int passes = 48 / JP;
  for (int p = 0; p < passes; ++p) {
    gemm1_k<<<dim3(96 * JP), dim3(256), 0, stream>>>(xb, w1t, e_b1, g_b1, tidx, h_ws, p * JP, JP);
    gemm2_k<<<dim3(24 * JP), dim3(256), 0, stream>>>(h_ws, w2t, e_b2, g_b2, x_f, tidx, so, outp, p * JP, JP);
  }
  final_ln_k<<<dim3(B_ * L_), dim3(256), 0, stream>>>(outp, so, gates, tidx,
                                                      e_gam, e_bet, g_gam, g_bet);
}

// Round 12
// 633.364 us; speedup vs baseline: 3.2804x; 3.2804x over previous
//
#include <hip/hip_runtime.h>
#include <cstdint>

#define B_    16
#define L_    512
#define D_    768
#define DFF_  3072
#define DLLM_ 4096
#define E_    8

typedef unsigned short ushort_t;
typedef __attribute__((ext_vector_type(4))) float accfrag_t;
typedef __attribute__((ext_vector_type(8))) short bfrag_t;

typedef __attribute__((address_space(3))) uint32_t lds_u32;
typedef __attribute__((address_space(1))) uint32_t glb_u32;

__device__ inline void gload16(const void* g, void* l) {
  __builtin_amdgcn_global_load_lds((const glb_u32*)(uintptr_t)g,
                                   (lds_u32*)(uint32_t)(uintptr_t)l, 16, 0, 0);
}

__device__ inline ushort_t f2bf(float f) {
  uint32_t u = __float_as_uint(f);
  return (ushort_t)((u + 0x7FFFu + ((u >> 16) & 1u)) >> 16);  // RNE
}
__device__ inline float bf2f(ushort_t v) { return __uint_as_float(((uint32_t)v) << 16); }

#define MFMA16(a, b, c) __builtin_amdgcn_mfma_f32_16x16x32_bf16(a, b, c, 0, 0, 0)

// ---------------------------------------------------------------------------
// m97-class 128x128 tile GEMM, BK=64, 4 waves (2Mx2N), 256 threads,
// single 32KB LDS buffer, 2 barriers/K-step, FOUR blocks/CU.
// Occupancy ladder evidence: 1 blk/CU (r5/6/7/10) ~10B/cyc/CU delivered;
// 3 blk/CU (r9) ~17B/cyc.  VGPR=76 allows at most 4 waves/SIMD (m69 steps
// at 64/128), i.e. 4 blocks/CU; (256,5) forced 48 VGPR + spill (r11, 2ms).
// (256,4): budget 128 >= 76, no codegen change, one more resident block.
// Swizzle: 16B chunk lc of row r stored at lc ^ (r&7), folded into the
// pre-swizzled GLOBAL source + ds_read offsets.  Measured 0 conflicts.
// ---------------------------------------------------------------------------
template <int KT>  // KT = K/64
__device__ __forceinline__ void gemm_body(const char* gA, const char* gB,
                                          char* sm, accfrag_t acc[4][4]) {
  const int tid = threadIdx.x;
  const int lane = tid & 63;
  const int w = tid >> 6, wm = w >> 1, wn = w & 1;
  const int LDB = KT * 128;  // row stride bytes (= K*2)

  const int R0 = tid >> 3;
  const char* srcA = gA + (size_t)R0 * LDB + ((((tid & 7) ^ (R0 & 7)) << 4));
  const char* srcB = gB + (size_t)R0 * LDB + ((((tid & 7) ^ (R0 & 7)) << 4));
  const int dl = tid * 16;

  const int l15 = lane & 15, l7 = lane & 7, lhi = lane >> 4;
  const int a0 = (wm * 64 + l15) * 128 + ((lhi ^ l7) << 4);
  const int a1 = (wm * 64 + l15) * 128 + (((4 + lhi) ^ l7) << 4);
  const int b0 = 16384 + (wn * 64 + l15) * 128 + ((lhi ^ l7) << 4);
  const int b1 = 16384 + (wn * 64 + l15) * 128 + (((4 + lhi) ^ l7) << 4);

#pragma unroll 1
  for (int t = 0; t < KT; ++t) {
    const size_t ko = (size_t)t * 128;
#pragma unroll
    for (int j = 0; j < 4; ++j)
      gload16(srcA + (size_t)j * 32 * LDB + ko, sm + j * 4096 + dl);
#pragma unroll
    for (int j = 0; j < 4; ++j)
      gload16(srcB + (size_t)j * 32 * LDB + ko, sm + 16384 + j * 4096 + dl);
    __syncthreads();
    bfrag_t af0[4], af1[4], bf0[4], bf1[4];
#pragma unroll
    for (int nf = 0; nf < 4; ++nf) {
      bf0[nf] = *(const bfrag_t*)(sm + b0 + nf * 2048);
      bf1[nf] = *(const bfrag_t*)(sm + b1 + nf * 2048);
    }
#pragma unroll
    for (int mf = 0; mf < 4; ++mf) {
      af0[mf] = *(const bfrag_t*)(sm + a0 + mf * 2048);
      af1[mf] = *(const bfrag_t*)(sm + a1 + mf * 2048);
    }
    __builtin_amdgcn_s_setprio(1);
#pragma unroll
    for (int mf = 0; mf < 4; ++mf)
#pragma unroll
      for (int nf = 0; nf < 4; ++nf) {
        acc[mf][nf] = MFMA16(af0[mf], bf0[nf], acc[mf][nf]);
        acc[mf][nf] = MFMA16(af1[mf], bf1[nf], acc[mf][nf]);
      }
    __builtin_amdgcn_s_setprio(0);
    __syncthreads();
  }
}

// XCD job-clustering remap (bijective when JP%8==0): physical flat id f runs
// on XCD f%8 [m09]; map so ALL blocks of a job share one XCD -> its L2 holds
// that job's weight/x panels instead of 8 jobs' worth.
__device__ inline void job_tile(int f, int tilesPerJob, int jp_count,
                                int& jobIdx, int& t) {
  if ((jp_count & 7) == 0) {
    const int xcd = f & 7, slot = f >> 3;
    jobIdx = xcd + 8 * (slot / tilesPerJob);
    t = slot % tilesPerJob;
  } else {
    jobIdx = f / tilesPerJob;
    t = f % tilesPerJob;
  }
}

// ---------------------------------------------------------------------------
// GEMM1: h = GELU_tanh(x @ W1 + b1), bf16 out [JP][512][3072]
// 1D grid 96*JP; tile t: mt = t/24 (A-panel-major), nt = t%24.
// Direct global_store_short epilogue (no LDS round-trip, no barriers).
// ---------------------------------------------------------------------------
__global__ __launch_bounds__(256, 4)
void gemm1_k(const ushort_t* __restrict__ xb, const ushort_t* __restrict__ w1t,
             const float* __restrict__ e_b1, const float* __restrict__ g_b1,
             const int* __restrict__ tidx, ushort_t* __restrict__ h_out,
             int job0, int jp_count) {
  __shared__ char sm[32768];
  int jp, t;
  job_tile(blockIdx.x, 96, jp_count, jp, t);
  const int mt = t / 24, nt = t % 24;
  const int job = job0 + jp;
  const int b = job / 3, s = job - b * 3;
  const int e = (s < 2) ? tidx[b * 2 + s] : E_;
  const char* gA = (const char*)(xb + ((size_t)b * L_ + mt * 128) * D_);
  const char* gB = (const char*)(w1t + ((size_t)e * DFF_ + nt * 128) * D_);
  accfrag_t acc[4][4] = {};
  gemm_body<12>(gA, gB, sm, acc);

  const float* b1 = (s < 2) ? (e_b1 + (size_t)e * DFF_) : g_b1;
  const int lane = threadIdx.x & 63, w = threadIdx.x >> 6;
  const int wm = w >> 1, wn = w & 1;
  const int row0 = mt * 128 + wm * 64 + ((lane >> 4) << 2);
  const int col0 = nt * 128 + wn * 64 + (lane & 15);
  float bias[4];
#pragma unroll
  for (int nf = 0; nf < 4; ++nf) bias[nf] = b1[col0 + nf * 16];
  ushort_t* hp = h_out + (size_t)jp * L_ * DFF_ + (size_t)row0 * DFF_ + col0;
#pragma unroll
  for (int mf = 0; mf < 4; ++mf)
#pragma unroll
    for (int r = 0; r < 4; ++r) {
      ushort_t* hr_ = hp + (size_t)(mf * 16 + r) * DFF_;
#pragma unroll
      for (int nf = 0; nf < 4; ++nf) {
        float v = acc[mf][nf][r] + bias[nf];
        float u = 0.7978845608028654f * (v + 0.044715f * v * v * v);
        float th = 1.0f - 2.0f / (1.0f + __expf(2.0f * u));  // tanh(u)
        hr_[nf * 16] = f2bf(0.5f * v * (1.0f + th));
      }
    }
}

// ---------------------------------------------------------------------------
// GEMM2: o = h @ W2 + b2 + x.  s<2 -> bf16 slot buffer; s==2 -> f32 d_out.
// 1D grid 24*JP; tile t: mt = t/6 (A-panel-major), nt = t%6.
// ---------------------------------------------------------------------------
__global__ __launch_bounds__(256, 4)
void gemm2_k(const ushort_t* __restrict__ h_in, const ushort_t* __restrict__ w2t,
             const float* __restrict__ e_b2, const float* __restrict__ g_b2,
             const float* __restrict__ x_f, const int* __restrict__ tidx,
             ushort_t* __restrict__ slot_o, float* __restrict__ outp,
             int job0, int jp_count) {
  __shared__ char sm[32768];
  int jp, t;
  job_tile(blockIdx.x, 24, jp_count, jp, t);
  const int mt = t / 6, nt = t % 6;
  const int job = job0 + jp;
  const int b = job / 3, s = job - b * 3;
  const int e = (s < 2) ? tidx[b * 2 + s] : E_;
  const char* gA = (const char*)(h_in + ((size_t)jp * L_ + mt * 128) * DFF_);
  const char* gB = (const char*)(w2t + ((size_t)e * D_ + nt * 128) * DFF_);
  accfrag_t acc[4][4] = {};
  gemm_body<48>(gA, gB, sm, acc);

  const float* b2 = (s < 2) ? (e_b2 + (size_t)e * D_) : g_b2;
  const int lane = threadIdx.x & 63, w = threadIdx.x >> 6;
  const int wm = w >> 1, wn = w & 1;
  const int row0 = mt * 128 + wm * 64 + ((lane >> 4) << 2);
  const int col0 = nt * 128 + wn * 64 + (lane & 15);
  float bias[4];
#pragma unroll
  for (int nf = 0; nf < 4; ++nf) bias[nf] = b2[col0 + nf * 16];
#pragma unroll
  for (int mf = 0; mf < 4; ++mf)
#pragma unroll
    for (int r = 0; r < 4; ++r) {
      const int row = row0 + mf * 16 + r;
      const float* xr = x_f + ((size_t)b * L_ + row) * D_ + col0;
#pragma unroll
      for (int nf = 0; nf < 4; ++nf) {
        float v = acc[mf][nf][r] + bias[nf] + xr[nf * 16];
        if (s < 2)
          slot_o[(((size_t)b * 2 + s) * L_ + row) * D_ + col0 + nf * 16] = f2bf(v);
        else
          outp[((size_t)b * L_ + row) * D_ + col0 + nf * 16] = v;
      }
    }
}

// ---------------------------------------------------------------------------
// Weight transpose + f32->bf16: src [R][C] f32 (8 experts + general)
// -> dst [9][C][R] bf16.  64x64 tiles; out[c][r] = tile[r][c].
// ---------------------------------------------------------------------------
__global__ __launch_bounds__(256)
void transpose_cvt_k(const float* __restrict__ srcE, const float* __restrict__ srcG,
                     ushort_t* __restrict__ dst, int R, int C) {
  const int z = blockIdx.z;
  const float* src = (z < 8) ? (srcE + (size_t)z * R * C) : srcG;
  ushort_t* out = dst + (size_t)z * R * C;
  __shared__ float tile[64][65];
  const int c0 = blockIdx.x * 64, r0 = blockIdx.y * 64;
  const int t = threadIdx.x;
  const int rr = t >> 4, cc = (t & 15) * 4;
#pragma unroll
  for (int i = 0; i < 4; ++i) {
    const float4 v = *(const float4*)(src + (size_t)(r0 + rr + i * 16) * C + c0 + cc);
    tile[rr + i * 16][cc] = v.x; tile[rr + i * 16][cc + 1] = v.y;
    tile[rr + i * 16][cc + 2] = v.z; tile[rr + i * 16][cc + 3] = v.w;
  }
  __syncthreads();
  const int c = t >> 2, r8 = (t & 3) * 16;
#pragma unroll
  for (int j = 0; j < 2; ++j) {
    ushort_t u[8];
#pragma unroll
    for (int k = 0; k < 8; ++k) u[k] = f2bf(tile[r8 + j * 8 + k][c]);
    *(uint4*)(out + (size_t)(c0 + c) * R + r0 + r8 + j * 8) = *(const uint4*)u;
  }
}

__global__ void cvt_x_k(const float* __restrict__ in, ushort_t* __restrict__ out) {
  const int i = (blockIdx.x * 256 + threadIdx.x) * 4;
  const float4 v = *(const float4*)(in + i);
  uint2 u;
  u.x = (uint32_t)f2bf(v.x) | ((uint32_t)f2bf(v.y) << 16);
  u.y = (uint32_t)f2bf(v.z) | ((uint32_t)f2bf(v.w) << 16);
  *(uint2*)(out + i) = u;
}

// ---------------------------------------------------------------------------
// Router: h = relu(emb @ We + cyc*Wc + b)
// ---------------------------------------------------------------------------
__global__ __launch_bounds__(256)
void router_partial_k(const float* __restrict__ emb, const float* __restrict__ We,
                      float* __restrict__ rp) {
  const int nt = blockIdx.x, kb = blockIdx.y;  // 12 x 16
  const int tid = threadIdx.x;
  __shared__ float semb[B_][256];
  const int k0 = kb * 256;
#pragma unroll
  for (int r = 0; r < B_; ++r) semb[r][tid] = emb[(size_t)r * DLLM_ + k0 + tid];
  __syncthreads();
  const int f = nt * 256 + tid;
  float acc[B_] = {};
  for (int k = 0; k < 256; ++k) {
    const float wv = We[(size_t)(k0 + k) * DFF_ + f];
#pragma unroll
    for (int j = 0; j < B_; ++j) acc[j] += semb[j][k] * wv;
  }
#pragma unroll
  for (int j = 0; j < B_; ++j)
    rp[((size_t)kb * B_ + j) * DFF_ + f] = acc[j];
}

__global__ void router_reduce_k(const float* __restrict__ rp, const float* __restrict__ cyc,
                                const float* __restrict__ Wc, const float* __restrict__ gb,
                                float* __restrict__ hr) {
  const int g = blockIdx.x * 256 + threadIdx.x;
  const int b = g / DFF_, f = g - b * DFF_;
  float s = 0.0f;
#pragma unroll
  for (int kb = 0; kb < 16; ++kb)
    s += rp[((size_t)kb * B_ + b) * DFF_ + f];
  s += cyc[b] * Wc[f] + gb[f];
  hr[(size_t)b * DFF_ + f] = fmaxf(s, 0.0f);
}

__global__ void router_final_k(const float* __restrict__ hr, const float* __restrict__ Wo,
                               const float* __restrict__ bo, int* __restrict__ tidx,
                               float* __restrict__ gates) {
  const int b = blockIdx.x, tid = threadIdx.x;
  float acc[E_] = {};
  for (int f = tid; f < DFF_; f += 256) {
    const float hv = hr[(size_t)b * DFF_ + f];
#pragma unroll
    for (int o = 0; o < E_; ++o) acc[o] += hv * Wo[(size_t)f * E_ + o];
  }
  __shared__ float lred[E_][4];
#pragma unroll
  for (int o = 0; o < E_; ++o) {
    float v = acc[o];
#pragma unroll
    for (int off = 32; off > 0; off >>= 1) v += __shfl_down(v, off, 64);
    if ((tid & 63) == 0) lred[o][tid >> 6] = v;
  }
  __syncthreads();
  if (tid == 0) {
    float lg[E_];
    float mx = -1e30f;
    for (int o = 0; o < E_; ++o) {
      lg[o] = lred[o][0] + lred[o][1] + lred[o][2] + lred[o][3] + bo[o];
      mx = fmaxf(mx, lg[o]);
    }
    int i1 = 0;
    for (int o = 1; o < E_; ++o) if (lg[o] > lg[i1]) i1 = o;
    int i2 = (i1 == 0) ? 1 : 0;
    for (int o = 0; o < E_; ++o) if (o != i1 && lg[o] > lg[i2]) i2 = o;
    float p[E_], sum = 0.0f;
    for (int o = 0; o < E_; ++o) { p[o] = __expf(lg[o] - mx); sum += p[o]; }
    const float p1 = p[i1] / sum, p2 = p[i2] / sum;
    const float den = p1 + p2 + 1e-9f;
    tidx[b * 2] = i1; tidx[b * 2 + 1] = i2;
    gates[b * 2] = p1 / den; gates[b * 2 + 1] = p2 / den;
  }
}

// ---------------------------------------------------------------------------
// Final: 3-way LayerNorm + gating + bf16 cast of combined; f32 output.
// ---------------------------------------------------------------------------
__global__ __launch_bounds__(256)
void final_ln_k(float* __restrict__ outp, const ushort_t* __restrict__ so,
                const float* __restrict__ gates, const int* __restrict__ tidx,
                const float* __restrict__ e_gam, const float* __restrict__ e_bet,
                const float* __restrict__ g_gam, const float* __restrict__ g_bet) {
  const int row = blockIdx.x;
  const int b = row >> 9, l = row & 511;
  const int tid = threadIdx.x;
  __shared__ float red4[4];
  float* gr = outp + (size_t)row * D_;
  const ushort_t* s0 = so + (((size_t)b * 2 + 0) * L_ + l) * D_;
  const ushort_t* s1 = so + (((size_t)b * 2 + 1) * L_ + l) * D_;
  float a0[3], a1[3], a2[3];
#pragma unroll
  for (int j = 0; j < 3; ++j) {
    const int d = tid + j * 256;
    a0[j] = gr[d];
    a1[j] = bf2f(s0[d]);
    a2[j] = bf2f(s1[d]);
  }
  auto bsum = [&](float v) -> float {
#pragma unroll
    for (int o = 32; o > 0; o >>= 1) v += __shfl_down(v, o, 64);
    if ((tid & 63) == 0) red4[tid >> 6] = v;
    __syncthreads();
    const float r = red4[0] + red4[1] + red4[2] + red4[3];
    __syncthreads();
    return r;
  };
  const float sg = bsum(a0[0] + a0[1] + a0[2]);
  const float qg = bsum(a0[0] * a0[0] + a0[1] * a0[1] + a0[2] * a0[2]);
  const float s0s = bsum(a1[0] + a1[1] + a1[2]);
  const float q0s = bsum(a1[0] * a1[0] + a1[1] * a1[1] + a1[2] * a1[2]);
  const float s1s = bsum(a2[0] + a2[1] + a2[2]);
  const float q1s = bsum(a2[0] * a2[0] + a2[1] * a2[1] + a2[2] * a2[2]);
  const float inv = 1.0f / 768.0f;
  const float mug = sg * inv, rg = rsqrtf(qg * inv - mug * mug + 1e-5f);
  const float mu0 = s0s * inv, r0 = rsqrtf(q0s * inv - mu0 * mu0 + 1e-5f);
  const float mu1 = s1s * inv, r1 = rsqrtf(q1s * inv - mu1 * mu1 + 1e-5f);
  const int e0 = tidx[b * 2], e1 = tidx[b * 2 + 1];
  const float g0 = gates[b * 2], g1 = gates[b * 2 + 1];
#pragma unroll
  for (int j = 0; j < 3; ++j) {
    const int d = tid + j * 256;
    const float lng = (a0[j] - mug) * rg * g_gam[d] + g_bet[d];
    const float ln0 = (a1[j] - mu0) * r0 * e_gam[(size_t)e0 * D_ + d] + e_bet[(size_t)e0 * D_ + d];
    const float ln1 = (a2[j] - mu1) * r1 * e_gam[(size_t)e1 * D_ + d] + e_bet[(size_t)e1 * D_ + d];
    const float comb = g0 * ln0 + g1 * ln1;
    gr[d] = lng + bf2f(f2bf(comb));
  }
}

// ---------------------------------------------------------------------------
extern "C" void kernel_launch(void* const* d_in, const int* in_sizes, int n_in,
                              void* d_out, int out_size, void* d_ws, size_t ws_size,
                              hipStream_t stream) {
  const float* x_f  = (const float*)d_in[0];
  const float* cyc  = (const float*)d_in[1];
  const float* emb  = (const float*)d_in[2];
  const float* We   = (const float*)d_in[3];
  const float* Wc   = (const float*)d_in[4];
  const float* gb   = (const float*)d_in[5];
  const float* Wo   = (const float*)d_in[6];
  const float* bo   = (const float*)d_in[7];
  const float* e_w1 = (const float*)d_in[8];
  const float* e_b1 = (const float*)d_in[9];
  const float* e_w2 = (const float*)d_in[10];
  const float* e_b2 = (const float*)d_in[11];
  const float* e_gam = (const float*)d_in[12];
  const float* e_bet = (const float*)d_in[13];
  const float* g_w1 = (const float*)d_in[14];
  const float* g_b1 = (const float*)d_in[15];
  const float* g_w2 = (const float*)d_in[16];
  const float* g_b2 = (const float*)d_in[17];
  const float* g_gam = (const float*)d_in[18];
  const float* g_bet = (const float*)d_in[19];
  float* outp = (float*)d_out;
  char* ws = (char*)d_ws;

  size_t off = 0;
  auto alloc = [&](size_t bytes) { size_t o = off; off = (off + bytes + 255) & ~(size_t)255; return o; };
  const size_t o_idx  = alloc(32 * 4);
  const size_t o_gate = alloc(32 * 4);
  const size_t o_hr   = alloc((size_t)B_ * DFF_ * 4);
  const size_t o_rp   = alloc((size_t)16 * B_ * DFF_ * 4);
  const size_t o_xb   = alloc((size_t)B_ * L_ * D_ * 2);
  const size_t o_w1t  = alloc((size_t)9 * DFF_ * D_ * 2);
  const size_t o_w2t  = alloc((size_t)9 * D_ * DFF_ * 2);
  const size_t o_so   = alloc((size_t)B_ * 2 * L_ * D_ * 2);
  const size_t o_h    = off;

  int JP = 1;
  const int divs[10] = {48, 24, 16, 12, 8, 6, 4, 3, 2, 1};
  for (int k = 0; k < 10; ++k) {
    if (o_h + (size_t)divs[k] * L_ * DFF_ * 2 <= ws_size) { JP = divs[k]; break; }
  }

  ushort_t* xb    = (ushort_t*)(ws + o_xb);
  ushort_t* w1t   = (ushort_t*)(ws + o_w1t);
  ushort_t* w2t   = (ushort_t*)(ws + o_w2t);
  ushort_t* so    = (ushort_t*)(ws + o_so);
  ushort_t* h_ws  = (ushort_t*)(ws + o_h);
  int*      tidx  = (int*)(ws + o_idx);
  float*    gates = (float*)(ws + o_gate);
  float*    hr    = (float*)(ws + o_hr);
  float*    rp    = (float*)(ws + o_rp);

  cvt_x_k<<<dim3((B_ * L_ * D_) / 1024), dim3(256), 0, stream>>>(x_f, xb);
  transpose_cvt_k<<<dim3(DFF_ / 64, D_ / 64, 9), dim3(256), 0, stream>>>(e_w1, g_w1, w1t, D_, DFF_);
  transpose_cvt_k<<<dim3(D_ / 64, DFF_ / 64, 9), dim3(256), 0, stream>>>(e_w2, g_w2, w2t, DFF_, D_);
  router_partial_k<<<dim3(12, 16), dim3(256), 0, stream>>>(emb, We, rp);
  router_reduce_k<<<dim3(192), dim3(256), 0, stream>>>(rp, cyc, Wc, gb, hr);
  router_final_k<<<dim3(16), dim3(256), 0, stream>>>(hr, Wo, bo, tidx, gates);

  const int passes = 48 / JP;
  for (int p = 0; p < passes; ++p) {
    gemm1_k<<<dim3(96 * JP), dim3(256), 0, stream>>>(xb, w1t, e_b1, g_b1, tidx, h_ws, p * JP, JP);
    gemm2_k<<<dim3(24 * JP), dim3(256), 0, stream>>>(h_ws, w2t, e_b2, g_b2, x_f, tidx, so, outp, p * JP, JP);
  }
  final_ln_k<<<dim3(B_ * L_), dim3(256), 0, stream>>>(outp, so, gates, tidx,
                                                      e_gam, e_bet, g_gam, g_bet);
}

// Round 13
// 477.811 us; speedup vs baseline: 4.3484x; 1.3256x over previous
//
#include <hip/hip_runtime.h>
#include <cstdint>

#define B_    16
#define L_    512
#define D_    768
#define DFF_  3072
#define DLLM_ 4096
#define E_    8

typedef unsigned short ushort_t;
typedef __attribute__((ext_vector_type(4))) float accfrag_t;
typedef __attribute__((ext_vector_type(8))) short bfrag_t;

typedef __attribute__((address_space(3))) uint32_t lds_u32;
typedef __attribute__((address_space(1))) uint32_t glb_u32;

__device__ inline void gload16(const void* g, void* l) {
  __builtin_amdgcn_global_load_lds((const glb_u32*)(uintptr_t)g,
                                   (lds_u32*)(uint32_t)(uintptr_t)l, 16, 0, 0);
}

__device__ inline ushort_t f2bf(float f) {
  uint32_t u = __float_as_uint(f);
  return (ushort_t)((u + 0x7FFFu + ((u >> 16) & 1u)) >> 16);  // RNE
}
__device__ inline float bf2f(ushort_t v) { return __uint_as_float(((uint32_t)v) << 16); }

#define MFMA16(a, b, c) __builtin_amdgcn_mfma_f32_16x16x32_bf16(a, b, c, 0, 0, 0)

// ---------------------------------------------------------------------------
// m97-class 128x128 tile GEMM, BK=64, 4 waves (2Mx2N), 256 threads,
// single 32KB LDS buffer, 2 barriers/K-step, targeting FOUR blocks/CU.
// Register budget engineering (r11/r12 lesson): CSV VGPR_Count is arch-VGPRs;
// the 64-reg fp32 accumulator lives in the same unified file.  r9's body kept
// 16 frags live (64 regs) at MFMA time -> 140 combined -> HW caps at 3
// waves/SIMD; forcing 4 made the allocator spill (WRITE_SIZE 49->190MB).
// Fix: split each K-iter into two k-halves, each {read 8 frags -> 16 MFMA},
// reusing the same 8 frag registers.  Live set ~116 combined < 128 -> 4
// blocks/CU legal WITHOUT spill.  sched_barrier(0) pins half-2 reads below
// half-1 MFMAs so the scheduler can't re-inflate pressure.
// Swizzle: 16B chunk lc of row r stored at lc ^ (r&7), folded into the
// pre-swizzled GLOBAL source + ds_read offsets.  Measured 0 conflicts.
// ---------------------------------------------------------------------------
template <int KT>  // KT = K/64
__device__ __forceinline__ void gemm_body(const char* gA, const char* gB,
                                          char* sm, accfrag_t acc[4][4]) {
  const int tid = threadIdx.x;
  const int lane = tid & 63;
  const int w = tid >> 6, wm = w >> 1, wn = w & 1;
  const int LDB = KT * 128;  // row stride bytes (= K*2)

  const int R0 = tid >> 3;
  const char* srcA = gA + (size_t)R0 * LDB + ((((tid & 7) ^ (R0 & 7)) << 4));
  const char* srcB = gB + (size_t)R0 * LDB + ((((tid & 7) ^ (R0 & 7)) << 4));
  const int dl = tid * 16;

  const int l15 = lane & 15, l7 = lane & 7, lhi = lane >> 4;
  const int a0 = (wm * 64 + l15) * 128 + ((lhi ^ l7) << 4);
  const int a1 = (wm * 64 + l15) * 128 + (((4 + lhi) ^ l7) << 4);
  const int b0 = 16384 + (wn * 64 + l15) * 128 + ((lhi ^ l7) << 4);
  const int b1 = 16384 + (wn * 64 + l15) * 128 + (((4 + lhi) ^ l7) << 4);

#pragma unroll 1
  for (int t = 0; t < KT; ++t) {
    const size_t ko = (size_t)t * 128;
#pragma unroll
    for (int j = 0; j < 4; ++j)
      gload16(srcA + (size_t)j * 32 * LDB + ko, sm + j * 4096 + dl);
#pragma unroll
    for (int j = 0; j < 4; ++j)
      gload16(srcB + (size_t)j * 32 * LDB + ko, sm + 16384 + j * 4096 + dl);
    __syncthreads();
    {  // k-half 0 (k = 0..31): 8 live frags only
      bfrag_t af[4], bf[4];
#pragma unroll
      for (int nf = 0; nf < 4; ++nf) bf[nf] = *(const bfrag_t*)(sm + b0 + nf * 2048);
#pragma unroll
      for (int mf = 0; mf < 4; ++mf) af[mf] = *(const bfrag_t*)(sm + a0 + mf * 2048);
      __builtin_amdgcn_s_setprio(1);
#pragma unroll
      for (int mf = 0; mf < 4; ++mf)
#pragma unroll
        for (int nf = 0; nf < 4; ++nf)
          acc[mf][nf] = MFMA16(af[mf], bf[nf], acc[mf][nf]);
      __builtin_amdgcn_s_setprio(0);
    }
    __builtin_amdgcn_sched_barrier(0);  // keep half-1 reads below half-0 MFMAs
    {  // k-half 1 (k = 32..63), same registers
      bfrag_t af[4], bf[4];
#pragma unroll
      for (int nf = 0; nf < 4; ++nf) bf[nf] = *(const bfrag_t*)(sm + b1 + nf * 2048);
#pragma unroll
      for (int mf = 0; mf < 4; ++mf) af[mf] = *(const bfrag_t*)(sm + a1 + mf * 2048);
      __builtin_amdgcn_s_setprio(1);
#pragma unroll
      for (int mf = 0; mf < 4; ++mf)
#pragma unroll
        for (int nf = 0; nf < 4; ++nf)
          acc[mf][nf] = MFMA16(af[mf], bf[nf], acc[mf][nf]);
      __builtin_amdgcn_s_setprio(0);
    }
    __syncthreads();
  }
}

// XCD job-clustering remap (bijective when JP%8==0): physical flat id f runs
// on XCD f%8 [m09]; map so ALL blocks of a job share one XCD -> its L2 holds
// that job's weight/x panels instead of 8 jobs' worth.
__device__ inline void job_tile(int f, int tilesPerJob, int jp_count,
                                int& jobIdx, int& t) {
  if ((jp_count & 7) == 0) {
    const int xcd = f & 7, slot = f >> 3;
    jobIdx = xcd + 8 * (slot / tilesPerJob);
    t = slot % tilesPerJob;
  } else {
    jobIdx = f / tilesPerJob;
    t = f % tilesPerJob;
  }
}

// ---------------------------------------------------------------------------
// GEMM1: h = GELU_tanh(x @ W1 + b1), bf16 out [JP][512][3072]
// 1D grid 96*JP; tile t: mt = t/24 (A-panel-major), nt = t%24.
// Direct global_store_short epilogue (no LDS round-trip, no barriers).
// ---------------------------------------------------------------------------
__global__ __launch_bounds__(256, 4)
void gemm1_k(const ushort_t* __restrict__ xb, const ushort_t* __restrict__ w1t,
             const float* __restrict__ e_b1, const float* __restrict__ g_b1,
             const int* __restrict__ tidx, ushort_t* __restrict__ h_out,
             int job0, int jp_count) {
  __shared__ char sm[32768];
  int jp, t;
  job_tile(blockIdx.x, 96, jp_count, jp, t);
  const int mt = t / 24, nt = t % 24;
  const int job = job0 + jp;
  const int b = job / 3, s = job - b * 3;
  const int e = (s < 2) ? tidx[b * 2 + s] : E_;
  const char* gA = (const char*)(xb + ((size_t)b * L_ + mt * 128) * D_);
  const char* gB = (const char*)(w1t + ((size_t)e * DFF_ + nt * 128) * D_);
  accfrag_t acc[4][4] = {};
  gemm_body<12>(gA, gB, sm, acc);

  const float* b1 = (s < 2) ? (e_b1 + (size_t)e * DFF_) : g_b1;
  const int lane = threadIdx.x & 63, w = threadIdx.x >> 6;
  const int wm = w >> 1, wn = w & 1;
  const int row0 = mt * 128 + wm * 64 + ((lane >> 4) << 2);
  const int col0 = nt * 128 + wn * 64 + (lane & 15);
  float bias[4];
#pragma unroll
  for (int nf = 0; nf < 4; ++nf) bias[nf] = b1[col0 + nf * 16];
  ushort_t* hp = h_out + (size_t)jp * L_ * DFF_ + (size_t)row0 * DFF_ + col0;
#pragma unroll
  for (int mf = 0; mf < 4; ++mf)
#pragma unroll
    for (int r = 0; r < 4; ++r) {
      ushort_t* hr_ = hp + (size_t)(mf * 16 + r) * DFF_;
#pragma unroll
      for (int nf = 0; nf < 4; ++nf) {
        float v = acc[mf][nf][r] + bias[nf];
        float u = 0.7978845608028654f * (v + 0.044715f * v * v * v);
        float th = 1.0f - 2.0f / (1.0f + __expf(2.0f * u));  // tanh(u)
        hr_[nf * 16] = f2bf(0.5f * v * (1.0f + th));
      }
    }
}

// ---------------------------------------------------------------------------
// GEMM2: o = h @ W2 + b2 + x.  s<2 -> bf16 slot buffer; s==2 -> f32 d_out.
// 1D grid 24*JP; tile t: mt = t/6 (A-panel-major), nt = t%6.
// ---------------------------------------------------------------------------
__global__ __launch_bounds__(256, 4)
void gemm2_k(const ushort_t* __restrict__ h_in, const ushort_t* __restrict__ w2t,
             const float* __restrict__ e_b2, const float* __restrict__ g_b2,
             const float* __restrict__ x_f, const int* __restrict__ tidx,
             ushort_t* __restrict__ slot_o, float* __restrict__ outp,
             int job0, int jp_count) {
  __shared__ char sm[32768];
  int jp, t;
  job_tile(blockIdx.x, 24, jp_count, jp, t);
  const int mt = t / 6, nt = t % 6;
  const int job = job0 + jp;
  const int b = job / 3, s = job - b * 3;
  const int e = (s < 2) ? tidx[b * 2 + s] : E_;
  const char* gA = (const char*)(h_in + ((size_t)jp * L_ + mt * 128) * DFF_);
  const char* gB = (const char*)(w2t + ((size_t)e * D_ + nt * 128) * DFF_);
  accfrag_t acc[4][4] = {};
  gemm_body<48>(gA, gB, sm, acc);

  const float* b2 = (s < 2) ? (e_b2 + (size_t)e * D_) : g_b2;
  const int lane = threadIdx.x & 63, w = threadIdx.x >> 6;
  const int wm = w >> 1, wn = w & 1;
  const int row0 = mt * 128 + wm * 64 + ((lane >> 4) << 2);
  const int col0 = nt * 128 + wn * 64 + (lane & 15);
  float bias[4];
#pragma unroll
  for (int nf = 0; nf < 4; ++nf) bias[nf] = b2[col0 + nf * 16];
#pragma unroll
  for (int mf = 0; mf < 4; ++mf)
#pragma unroll
    for (int r = 0; r < 4; ++r) {
      const int row = row0 + mf * 16 + r;
      const float* xr = x_f + ((size_t)b * L_ + row) * D_ + col0;
#pragma unroll
      for (int nf = 0; nf < 4; ++nf) {
        float v = acc[mf][nf][r] + bias[nf] + xr[nf * 16];
        if (s < 2)
          slot_o[(((size_t)b * 2 + s) * L_ + row) * D_ + col0 + nf * 16] = f2bf(v);
        else
          outp[((size_t)b * L_ + row) * D_ + col0 + nf * 16] = v;
      }
    }
}

// ---------------------------------------------------------------------------
// Weight transpose + f32->bf16: src [R][C] f32 (8 experts + general)
// -> dst [9][C][R] bf16.  64x64 tiles; out[c][r] = tile[r][c].
// ---------------------------------------------------------------------------
__global__ __launch_bounds__(256)
void transpose_cvt_k(const float* __restrict__ srcE, const float* __restrict__ srcG,
                     ushort_t* __restrict__ dst, int R, int C) {
  const int z = blockIdx.z;
  const float* src = (z < 8) ? (srcE + (size_t)z * R * C) : srcG;
  ushort_t* out = dst + (size_t)z * R * C;
  __shared__ float tile[64][65];
  const int c0 = blockIdx.x * 64, r0 = blockIdx.y * 64;
  const int t = threadIdx.x;
  const int rr = t >> 4, cc = (t & 15) * 4;
#pragma unroll
  for (int i = 0; i < 4; ++i) {
    const float4 v = *(const float4*)(src + (size_t)(r0 + rr + i * 16) * C + c0 + cc);
    tile[rr + i * 16][cc] = v.x; tile[rr + i * 16][cc + 1] = v.y;
    tile[rr + i * 16][cc + 2] = v.z; tile[rr + i * 16][cc + 3] = v.w;
  }
  __syncthreads();
  const int c = t >> 2, r8 = (t & 3) * 16;
#pragma unroll
  for (int j = 0; j < 2; ++j) {
    ushort_t u[8];
#pragma unroll
    for (int k = 0; k < 8; ++k) u[k] = f2bf(tile[r8 + j * 8 + k][c]);
    *(uint4*)(out + (size_t)(c0 + c) * R + r0 + r8 + j * 8) = *(const uint4*)u;
  }
}

__global__ void cvt_x_k(const float* __restrict__ in, ushort_t* __restrict__ out) {
  const int i = (blockIdx.x * 256 + threadIdx.x) * 4;
  const float4 v = *(const float4*)(in + i);
  uint2 u;
  u.x = (uint32_t)f2bf(v.x) | ((uint32_t)f2bf(v.y) << 16);
  u.y = (uint32_t)f2bf(v.z) | ((uint32_t)f2bf(v.w) << 16);
  *(uint2*)(out + i) = u;
}

// ---------------------------------------------------------------------------
// Router: h = relu(emb @ We + cyc*Wc + b)
// ---------------------------------------------------------------------------
__global__ __launch_bounds__(256)
void router_partial_k(const float* __restrict__ emb, const float* __restrict__ We,
                      float* __restrict__ rp) {
  const int nt = blockIdx.x, kb = blockIdx.y;  // 12 x 16
  const int tid = threadIdx.x;
  __shared__ float semb[B_][256];
  const int k0 = kb * 256;
#pragma unroll
  for (int r = 0; r < B_; ++r) semb[r][tid] = emb[(size_t)r * DLLM_ + k0 + tid];
  __syncthreads();
  const int f = nt * 256 + tid;
  float acc[B_] = {};
  for (int k = 0; k < 256; ++k) {
    const float wv = We[(size_t)(k0 + k) * DFF_ + f];
#pragma unroll
    for (int j = 0; j < B_; ++j) acc[j] += semb[j][k] * wv;
  }
#pragma unroll
  for (int j = 0; j < B_; ++j)
    rp[((size_t)kb * B_ + j) * DFF_ + f] = acc[j];
}

__global__ void router_reduce_k(const float* __restrict__ rp, const float* __restrict__ cyc,
                                const float* __restrict__ Wc, const float* __restrict__ gb,
                                float* __restrict__ hr) {
  const int g = blockIdx.x * 256 + threadIdx.x;
  const int b = g / DFF_, f = g - b * DFF_;
  float s = 0.0f;
#pragma unroll
  for (int kb = 0; kb < 16; ++kb)
    s += rp[((size_t)kb * B_ + b) * DFF_ + f];
  s += cyc[b] * Wc[f] + gb[f];
  hr[(size_t)b * DFF_ + f] = fmaxf(s, 0.0f);
}

__global__ void router_final_k(const float* __restrict__ hr, const float* __restrict__ Wo,
                               const float* __restrict__ bo, int* __restrict__ tidx,
                               float* __restrict__ gates) {
  const int b = blockIdx.x, tid = threadIdx.x;
  float acc[E_] = {};
  for (int f = tid; f < DFF_; f += 256) {
    const float hv = hr[(size_t)b * DFF_ + f];
#pragma unroll
    for (int o = 0; o < E_; ++o) acc[o] += hv * Wo[(size_t)f * E_ + o];
  }
  __shared__ float lred[E_][4];
#pragma unroll
  for (int o = 0; o < E_; ++o) {
    float v = acc[o];
#pragma unroll
    for (int off = 32; off > 0; off >>= 1) v += __shfl_down(v, off, 64);
    if ((tid & 63) == 0) lred[o][tid >> 6] = v;
  }
  __syncthreads();
  if (tid == 0) {
    float lg[E_];
    float mx = -1e30f;
    for (int o = 0; o < E_; ++o) {
      lg[o] = lred[o][0] + lred[o][1] + lred[o][2] + lred[o][3] + bo[o];
      mx = fmaxf(mx, lg[o]);
    }
    int i1 = 0;
    for (int o = 1; o < E_; ++o) if (lg[o] > lg[i1]) i1 = o;
    int i2 = (i1 == 0) ? 1 : 0;
    for (int o = 0; o < E_; ++o) if (o != i1 && lg[o] > lg[i2]) i2 = o;
    float p[E_], sum = 0.0f;
    for (int o = 0; o < E_; ++o) { p[o] = __expf(lg[o] - mx); sum += p[o]; }
    const float p1 = p[i1] / sum, p2 = p[i2] / sum;
    const float den = p1 + p2 + 1e-9f;
    tidx[b * 2] = i1; tidx[b * 2 + 1] = i2;
    gates[b * 2] = p1 / den; gates[b * 2 + 1] = p2 / den;
  }
}

// ---------------------------------------------------------------------------
// Final: 3-way LayerNorm + gating + bf16 cast of combined; f32 output.
// ---------------------------------------------------------------------------
__global__ __launch_bounds__(256)
void final_ln_k(float* __restrict__ outp, const ushort_t* __restrict__ so,
                const float* __restrict__ gates, const int* __restrict__ tidx,
                const float* __restrict__ e_gam, const float* __restrict__ e_bet,
                const float* __restrict__ g_gam, const float* __restrict__ g_bet) {
  const int row = blockIdx.x;
  const int b = row >> 9, l = row & 511;
  const int tid = threadIdx.x;
  __shared__ float red4[4];
  float* gr = outp + (size_t)row * D_;
  const ushort_t* s0 = so + (((size_t)b * 2 + 0) * L_ + l) * D_;
  const ushort_t* s1 = so + (((size_t)b * 2 + 1) * L_ + l) * D_;
  float a0[3], a1[3], a2[3];
#pragma unroll
  for (int j = 0; j < 3; ++j) {
    const int d = tid + j * 256;
    a0[j] = gr[d];
    a1[j] = bf2f(s0[d]);
    a2[j] = bf2f(s1[d]);
  }
  auto bsum = [&](float v) -> float {
#pragma unroll
    for (int o = 32; o > 0; o >>= 1) v += __shfl_down(v, o, 64);
    if ((tid & 63) == 0) red4[tid >> 6] = v;
    __syncthreads();
    const float r = red4[0] + red4[1] + red4[2] + red4[3];
    __syncthreads();
    return r;
  };
  const float sg = bsum(a0[0] + a0[1] + a0[2]);
  const float qg = bsum(a0[0] * a0[0] + a0[1] * a0[1] + a0[2] * a0[2]);
  const float s0s = bsum(a1[0] + a1[1] + a1[2]);
  const float q0s = bsum(a1[0] * a1[0] + a1[1] * a1[1] + a1[2] * a1[2]);
  const float s1s = bsum(a2[0] + a2[1] + a2[2]);
  const float q1s = bsum(a2[0] * a2[0] + a2[1] * a2[1] + a2[2] * a2[2]);
  const float inv = 1.0f / 768.0f;
  const float mug = sg * inv, rg = rsqrtf(qg * inv - mug * mug + 1e-5f);
  const float mu0 = s0s * inv, r0 = rsqrtf(q0s * inv - mu0 * mu0 + 1e-5f);
  const float mu1 = s1s * inv, r1 = rsqrtf(q1s * inv - mu1 * mu1 + 1e-5f);
  const int e0 = tidx[b * 2], e1 = tidx[b * 2 + 1];
  const float g0 = gates[b * 2], g1 = gates[b * 2 + 1];
#pragma unroll
  for (int j = 0; j < 3; ++j) {
    const int d = tid + j * 256;
    const float lng = (a0[j] - mug) * rg * g_gam[d] + g_bet[d];
    const float ln0 = (a1[j] - mu0) * r0 * e_gam[(size_t)e0 * D_ + d] + e_bet[(size_t)e0 * D_ + d];
    const float ln1 = (a2[j] - mu1) * r1 * e_gam[(size_t)e1 * D_ + d] + e_bet[(size_t)e1 * D_ + d];
    const float comb = g0 * ln0 + g1 * ln1;
    gr[d] = lng + bf2f(f2bf(comb));
  }
}

// ---------------------------------------------------------------------------
extern "C" void kernel_launch(void* const* d_in, const int* in_sizes, int n_in,
                              void* d_out, int out_size, void* d_ws, size_t ws_size,
                              hipStream_t stream) {
  const float* x_f  = (const float*)d_in[0];
  const float* cyc  = (const float*)d_in[1];
  const float* emb  = (const float*)d_in[2];
  const float* We   = (const float*)d_in[3];
  const float* Wc   = (const float*)d_in[4];
  const float* gb   = (const float*)d_in[5];
  const float* Wo   = (const float*)d_in[6];
  const float* bo   = (const float*)d_in[7];
  const float* e_w1 = (const float*)d_in[8];
  const float* e_b1 = (const float*)d_in[9];
  const float* e_w2 = (const float*)d_in[10];
  const float* e_b2 = (const float*)d_in[11];
  const float* e_gam = (const float*)d_in[12];
  const float* e_bet = (const float*)d_in[13];
  const float* g_w1 = (const float*)d_in[14];
  const float* g_b1 = (const float*)d_in[15];
  const float* g_w2 = (const float*)d_in[16];
  const float* g_b2 = (const float*)d_in[17];
  const float* g_gam = (const float*)d_in[18];
  const float* g_bet = (const float*)d_in[19];
  float* outp = (float*)d_out;
  char* ws = (char*)d_ws;

  size_t off = 0;
  auto alloc = [&](size_t bytes) { size_t o = off; off = (off + bytes + 255) & ~(size_t)255; return o; };
  const size_t o_idx  = alloc(32 * 4);
  const size_t o_gate = alloc(32 * 4);
  const size_t o_hr   = alloc((size_t)B_ * DFF_ * 4);
  const size_t o_rp   = alloc((size_t)16 * B_ * DFF_ * 4);
  const size_t o_xb   = alloc((size_t)B_ * L_ * D_ * 2);
  const size_t o_w1t  = alloc((size_t)9 * DFF_ * D_ * 2);
  const size_t o_w2t  = alloc((size_t)9 * D_ * DFF_ * 2);
  const size_t o_so   = alloc((size_t)B_ * 2 * L_ * D_ * 2);
  const size_t o_h    = off;

  int JP = 1;
  const int divs[10] = {48, 24, 16, 12, 8, 6, 4, 3, 2, 1};
  for (int k = 0; k < 10; ++k) {
    if (o_h + (size_t)divs[k] * L_ * DFF_ * 2 <= ws_size) { JP = divs[k]; break; }
  }

  ushort_t* xb    = (ushort_t*)(ws + o_xb);
  ushort_t* w1t   = (ushort_t*)(ws + o_w1t);
  ushort_t* w2t   = (ushort_t*)(ws + o_w2t);
  ushort_t* so    = (ushort_t*)(ws + o_so);
  ushort_t* h_ws  = (ushort_t*)(ws + o_h);
  int*      tidx  = (int*)(ws + o_idx);
  float*    gates = (float*)(ws + o_gate);
  float*    hr    = (float*)(ws + o_hr);
  float*    rp    = (float*)(ws + o_rp);

  cvt_x_k<<<dim3((B_ * L_ * D_) / 1024), dim3(256), 0, stream>>>(x_f, xb);
  transpose_cvt_k<<<dim3(DFF_ / 64, D_ / 64, 9), dim3(256), 0, stream>>>(e_w1, g_w1, w1t, D_, DFF_);
  transpose_cvt_k<<<dim3(D_ / 64, DFF_ / 64, 9), dim3(256), 0, stream>>>(e_w2, g_w2, w2t, DFF_, D_);
  router_partial_k<<<dim3(12, 16), dim3(256), 0, stream>>>(emb, We, rp);
  router_reduce_k<<<dim3(192), dim3(256), 0, stream>>>(rp, cyc, Wc, gb, hr);
  router_final_k<<<dim3(16), dim3(256), 0, stream>>>(hr, Wo, bo, tidx, gates);

  const int passes = 48 / JP;
  for (int p = 0; p < passes; ++p) {
    gemm1_k<<<dim3(96 * JP), dim3(256), 0, stream>>>(xb, w1t, e_b1, g_b1, tidx, h_ws, p * JP, JP);
    gemm2_k<<<dim3(24 * JP), dim3(256), 0, stream>>>(h_ws, w2t, e_b2, g_b2, x_f, tidx, so, outp, p * JP, JP);
  }
  final_ln_k<<<dim3(B_ * L_), dim3(256), 0, stream>>>(outp, so, gates, tidx,
                                                      e_gam, e_bet, g_gam, g_bet);
}

// Round 14
// 437.341 us; speedup vs baseline: 4.7507x; 1.0925x over previous
//
#include <hip/hip_runtime.h>
#include <cstdint>

#define B_    16
#define L_    512
#define D_    768
#define DFF_  3072
#define DLLM_ 4096
#define E_    8

typedef unsigned short ushort_t;
typedef __attribute__((ext_vector_type(4))) float accfrag_t;
typedef __attribute__((ext_vector_type(8))) short bfrag_t;

typedef __attribute__((address_space(3))) uint32_t lds_u32;
typedef __attribute__((address_space(1))) uint32_t glb_u32;

__device__ inline void gload16(const void* g, void* l) {
  __builtin_amdgcn_global_load_lds((const glb_u32*)(uintptr_t)g,
                                   (lds_u32*)(uint32_t)(uintptr_t)l, 16, 0, 0);
}

__device__ inline ushort_t f2bf(float f) {
  uint32_t u = __float_as_uint(f);
  return (ushort_t)((u + 0x7FFFu + ((u >> 16) & 1u)) >> 16);  // RNE
}
__device__ inline float bf2f(ushort_t v) { return __uint_as_float(((uint32_t)v) << 16); }

#define MFMA16(a, b, c) __builtin_amdgcn_mfma_f32_16x16x32_bf16(a, b, c, 0, 0, 0)

// ---------------------------------------------------------------------------
// 128(M) x 192(N) tile GEMM, BK=64, 4 waves (2M x 2N, wave tile 64x96),
// 256 threads, single 40KB LDS buffer, 2 barriers/K-step, 3 blocks/CU.
// Rationale (r9/r13 measurements): per-CU staging delivery saturates at
// ~16 B/cyc regardless of resident blocks (3blk: 118us/block, 4blk: 162 =
// x4/3) => GEMM time ~= total staged bytes / 10 TB/s.  128x192 cuts staged
// bytes/FLOP 17% vs 128x128 and makes both grids EXACT multiples of the
// 768 resident-block capacity (gemm1 4.0 rounds, gemm2 1.0 -- r9's gemm2
// had a 1.5-round tail).  Register budget at 3 waves/SIMD (<=170 combined):
// acc 96 AGPR + 10 frags (40) + addr ~20 = ~156 -- fits via the k-half
// split (r13-proven, 60 arch VGPR, no spill).
// Swizzle: 16B chunk lc of row r stored at lc ^ (r&7), folded into the
// pre-swizzled GLOBAL source + ds_read offsets.  Measured 0 conflicts.
// Staging: A 4 chunks/thread (rows tid>>3 + j*32), B 6 chunks/thread;
// row step 32 === 0 mod 8 keeps the swizzle term invariant per thread.
// ---------------------------------------------------------------------------
template <int KT>  // KT = K/64
__device__ __forceinline__ void gemm_body(const char* gA, const char* gB,
                                          char* sm, accfrag_t acc[4][6]) {
  const int tid = threadIdx.x;
  const int lane = tid & 63;
  const int w = tid >> 6, wm = w >> 1, wn = w & 1;
  const int LDB = KT * 128;  // row stride bytes (= K*2)

  const int R0 = tid >> 3;  // 0..31
  const int swz = (((tid & 7) ^ (R0 & 7)) << 4);
  const char* srcA = gA + (size_t)R0 * LDB + swz;
  const char* srcB = gB + (size_t)R0 * LDB + swz;
  const int dl = tid * 16;

  const int l15 = lane & 15, l7 = lane & 7, lhi = lane >> 4;
  const int a0 = (wm * 64 + l15) * 128 + ((lhi ^ l7) << 4);
  const int a1 = (wm * 64 + l15) * 128 + (((4 + lhi) ^ l7) << 4);
  const int b0 = 16384 + (wn * 96 + l15) * 128 + ((lhi ^ l7) << 4);
  const int b1 = 16384 + (wn * 96 + l15) * 128 + (((4 + lhi) ^ l7) << 4);

#pragma unroll 1
  for (int t = 0; t < KT; ++t) {
    const size_t ko = (size_t)t * 128;
#pragma unroll
    for (int j = 0; j < 4; ++j)  // A: 128 rows
      gload16(srcA + (size_t)j * 32 * LDB + ko, sm + j * 4096 + dl);
#pragma unroll
    for (int j = 0; j < 6; ++j)  // B: 192 rows
      gload16(srcB + (size_t)j * 32 * LDB + ko, sm + 16384 + j * 4096 + dl);
    __syncthreads();
    {  // k-half 0 (k = 0..31)
      bfrag_t af[4], bf[6];
#pragma unroll
      for (int nf = 0; nf < 6; ++nf) bf[nf] = *(const bfrag_t*)(sm + b0 + nf * 2048);
#pragma unroll
      for (int mf = 0; mf < 4; ++mf) af[mf] = *(const bfrag_t*)(sm + a0 + mf * 2048);
      __builtin_amdgcn_s_setprio(1);
#pragma unroll
      for (int mf = 0; mf < 4; ++mf)
#pragma unroll
        for (int nf = 0; nf < 6; ++nf)
          acc[mf][nf] = MFMA16(af[mf], bf[nf], acc[mf][nf]);
      __builtin_amdgcn_s_setprio(0);
    }
    __builtin_amdgcn_sched_barrier(0);  // keep half-1 reads below half-0 MFMAs
    {  // k-half 1 (k = 32..63), same registers
      bfrag_t af[4], bf[6];
#pragma unroll
      for (int nf = 0; nf < 6; ++nf) bf[nf] = *(const bfrag_t*)(sm + b1 + nf * 2048);
#pragma unroll
      for (int mf = 0; mf < 4; ++mf) af[mf] = *(const bfrag_t*)(sm + a1 + mf * 2048);
      __builtin_amdgcn_s_setprio(1);
#pragma unroll
      for (int mf = 0; mf < 4; ++mf)
#pragma unroll
        for (int nf = 0; nf < 6; ++nf)
          acc[mf][nf] = MFMA16(af[mf], bf[nf], acc[mf][nf]);
      __builtin_amdgcn_s_setprio(0);
    }
    __syncthreads();
  }
}

// XCD job-clustering remap (bijective when JP%8==0): physical flat id f runs
// on XCD f%8 [m09]; map so all blocks of a job share one XCD.
__device__ inline void job_tile(int f, int tilesPerJob, int jp_count,
                                int& jobIdx, int& t) {
  if ((jp_count & 7) == 0) {
    const int xcd = f & 7, slot = f >> 3;
    jobIdx = xcd + 8 * (slot / tilesPerJob);
    t = slot % tilesPerJob;
  } else {
    jobIdx = f / tilesPerJob;
    t = f % tilesPerJob;
  }
}

// ---------------------------------------------------------------------------
// GEMM1: h = GELU_tanh(x @ W1 + b1), bf16 out [JP][512][3072]
// 1D grid 64*JP (= 3072 at JP=48 -> exactly 4.0 rounds of 768 slots).
// tile t: mt = t>>4 (A-panel-major), nt = t&15 (N tiles of 192).
// ---------------------------------------------------------------------------
__global__ __launch_bounds__(256, 3)
void gemm1_k(const ushort_t* __restrict__ xb, const ushort_t* __restrict__ w1t,
             const float* __restrict__ e_b1, const float* __restrict__ g_b1,
             const int* __restrict__ tidx, ushort_t* __restrict__ h_out,
             int job0, int jp_count) {
  __shared__ char sm[40960];
  int jp, t;
  job_tile(blockIdx.x, 64, jp_count, jp, t);
  const int mt = t >> 4, nt = t & 15;
  const int job = job0 + jp;
  const int b = job / 3, s = job - b * 3;
  const int e = (s < 2) ? tidx[b * 2 + s] : E_;
  const char* gA = (const char*)(xb + ((size_t)b * L_ + mt * 128) * D_);
  const char* gB = (const char*)(w1t + ((size_t)e * DFF_ + nt * 192) * D_);
  accfrag_t acc[4][6] = {};
  gemm_body<12>(gA, gB, sm, acc);

  const float* b1 = (s < 2) ? (e_b1 + (size_t)e * DFF_) : g_b1;
  const int lane = threadIdx.x & 63, w = threadIdx.x >> 6;
  const int wm = w >> 1, wn = w & 1;
  const int row0 = mt * 128 + wm * 64 + ((lane >> 4) << 2);
  const int col0 = nt * 192 + wn * 96 + (lane & 15);
  float bias[6];
#pragma unroll
  for (int nf = 0; nf < 6; ++nf) bias[nf] = b1[col0 + nf * 16];
  ushort_t* hp = h_out + (size_t)jp * L_ * DFF_ + (size_t)row0 * DFF_ + col0;
#pragma unroll
  for (int mf = 0; mf < 4; ++mf)
#pragma unroll
    for (int r = 0; r < 4; ++r) {
      ushort_t* hr_ = hp + (size_t)(mf * 16 + r) * DFF_;
#pragma unroll
      for (int nf = 0; nf < 6; ++nf) {
        float v = acc[mf][nf][r] + bias[nf];
        float u = 0.7978845608028654f * (v + 0.044715f * v * v * v);
        float th = 1.0f - 2.0f / (1.0f + __expf(2.0f * u));  // tanh(u)
        hr_[nf * 16] = f2bf(0.5f * v * (1.0f + th));
      }
    }
}

// ---------------------------------------------------------------------------
// GEMM2: o = h @ W2 + b2 + x.  s<2 -> bf16 slot buffer; s==2 -> f32 d_out.
// 1D grid 16*JP (= 768 at JP=48 -> exactly 1.0 round, no tail).
// tile t: mt = t>>2, nt = t&3 (N tiles of 192).
// ---------------------------------------------------------------------------
__global__ __launch_bounds__(256, 3)
void gemm2_k(const ushort_t* __restrict__ h_in, const ushort_t* __restrict__ w2t,
             const float* __restrict__ e_b2, const float* __restrict__ g_b2,
             const float* __restrict__ x_f, const int* __restrict__ tidx,
             ushort_t* __restrict__ slot_o, float* __restrict__ outp,
             int job0, int jp_count) {
  __shared__ char sm[40960];
  int jp, t;
  job_tile(blockIdx.x, 16, jp_count, jp, t);
  const int mt = t >> 2, nt = t & 3;
  const int job = job0 + jp;
  const int b = job / 3, s = job - b * 3;
  const int e = (s < 2) ? tidx[b * 2 + s] : E_;
  const char* gA = (const char*)(h_in + ((size_t)jp * L_ + mt * 128) * DFF_);
  const char* gB = (const char*)(w2t + ((size_t)e * D_ + nt * 192) * DFF_);
  accfrag_t acc[4][6] = {};
  gemm_body<48>(gA, gB, sm, acc);

  const float* b2 = (s < 2) ? (e_b2 + (size_t)e * D_) : g_b2;
  const int lane = threadIdx.x & 63, w = threadIdx.x >> 6;
  const int wm = w >> 1, wn = w & 1;
  const int row0 = mt * 128 + wm * 64 + ((lane >> 4) << 2);
  const int col0 = nt * 192 + wn * 96 + (lane & 15);
  float bias[6];
#pragma unroll
  for (int nf = 0; nf < 6; ++nf) bias[nf] = b2[col0 + nf * 16];
#pragma unroll
  for (int mf = 0; mf < 4; ++mf)
#pragma unroll
    for (int r = 0; r < 4; ++r) {
      const int row = row0 + mf * 16 + r;
      const float* xr = x_f + ((size_t)b * L_ + row) * D_ + col0;
#pragma unroll
      for (int nf = 0; nf < 6; ++nf) {
        float v = acc[mf][nf][r] + bias[nf] + xr[nf * 16];
        if (s < 2)
          slot_o[(((size_t)b * 2 + s) * L_ + row) * D_ + col0 + nf * 16] = f2bf(v);
        else
          outp[((size_t)b * L_ + row) * D_ + col0 + nf * 16] = v;
      }
    }
}

// ---------------------------------------------------------------------------
// Weight transpose + f32->bf16: src [R][C] f32 (8 experts + general)
// -> dst [9][C][R] bf16.  64x64 tiles; out[c][r] = tile[r][c].
// ---------------------------------------------------------------------------
__global__ __launch_bounds__(256)
void transpose_cvt_k(const float* __restrict__ srcE, const float* __restrict__ srcG,
                     ushort_t* __restrict__ dst, int R, int C) {
  const int z = blockIdx.z;
  const float* src = (z < 8) ? (srcE + (size_t)z * R * C) : srcG;
  ushort_t* out = dst + (size_t)z * R * C;
  __shared__ float tile[64][65];
  const int c0 = blockIdx.x * 64, r0 = blockIdx.y * 64;
  const int t = threadIdx.x;
  const int rr = t >> 4, cc = (t & 15) * 4;
#pragma unroll
  for (int i = 0; i < 4; ++i) {
    const float4 v = *(const float4*)(src + (size_t)(r0 + rr + i * 16) * C + c0 + cc);
    tile[rr + i * 16][cc] = v.x; tile[rr + i * 16][cc + 1] = v.y;
    tile[rr + i * 16][cc + 2] = v.z; tile[rr + i * 16][cc + 3] = v.w;
  }
  __syncthreads();
  const int c = t >> 2, r8 = (t & 3) * 16;
#pragma unroll
  for (int j = 0; j < 2; ++j) {
    ushort_t u[8];
#pragma unroll
    for (int k = 0; k < 8; ++k) u[k] = f2bf(tile[r8 + j * 8 + k][c]);
    *(uint4*)(out + (size_t)(c0 + c) * R + r0 + r8 + j * 8) = *(const uint4*)u;
  }
}

__global__ void cvt_x_k(const float* __restrict__ in, ushort_t* __restrict__ out) {
  const int i = (blockIdx.x * 256 + threadIdx.x) * 4;
  const float4 v = *(const float4*)(in + i);
  uint2 u;
  u.x = (uint32_t)f2bf(v.x) | ((uint32_t)f2bf(v.y) << 16);
  u.y = (uint32_t)f2bf(v.z) | ((uint32_t)f2bf(v.w) << 16);
  *(uint2*)(out + i) = u;
}

// ---------------------------------------------------------------------------
// Router stage 1: partial sums of relu-input (split-K over DLLM)
// ---------------------------------------------------------------------------
__global__ __launch_bounds__(256)
void router_partial_k(const float* __restrict__ emb, const float* __restrict__ We,
                      float* __restrict__ rp) {
  const int nt = blockIdx.x, kb = blockIdx.y;  // 12 x 16
  const int tid = threadIdx.x;
  __shared__ float semb[B_][256];
  const int k0 = kb * 256;
#pragma unroll
  for (int r = 0; r < B_; ++r) semb[r][tid] = emb[(size_t)r * DLLM_ + k0 + tid];
  __syncthreads();
  const int f = nt * 256 + tid;
  float acc[B_] = {};
  for (int k = 0; k < 256; ++k) {
    const float wv = We[(size_t)(k0 + k) * DFF_ + f];
#pragma unroll
    for (int j = 0; j < B_; ++j) acc[j] += semb[j][k] * wv;
  }
#pragma unroll
  for (int j = 0; j < B_; ++j)
    rp[((size_t)kb * B_ + j) * DFF_ + f] = acc[j];
}

// ---------------------------------------------------------------------------
// Router stage 2 (merged reduce + final): per batch b, reduce partials ->
// relu -> logits = h @ Wo + bo -> top2 + renormalized gates.
// ---------------------------------------------------------------------------
__global__ __launch_bounds__(256)
void router_final_k(const float* __restrict__ rp, const float* __restrict__ cyc,
                    const float* __restrict__ Wc, const float* __restrict__ gb,
                    const float* __restrict__ Wo, const float* __restrict__ bo,
                    int* __restrict__ tidx, float* __restrict__ gates) {
  const int b = blockIdx.x, tid = threadIdx.x;
  const float cycb = cyc[b];
  float acc[E_] = {};
#pragma unroll
  for (int fi = 0; fi < 12; ++fi) {
    const int f = tid + fi * 256;
    float sv = 0.0f;
#pragma unroll
    for (int kb = 0; kb < 16; ++kb)
      sv += rp[((size_t)kb * B_ + b) * DFF_ + f];
    sv += cycb * Wc[f] + gb[f];
    sv = fmaxf(sv, 0.0f);
#pragma unroll
    for (int o = 0; o < E_; ++o) acc[o] += sv * Wo[(size_t)f * E_ + o];
  }
  __shared__ float lred[E_][4];
#pragma unroll
  for (int o = 0; o < E_; ++o) {
    float v = acc[o];
#pragma unroll
    for (int off = 32; off > 0; off >>= 1) v += __shfl_down(v, off, 64);
    if ((tid & 63) == 0) lred[o][tid >> 6] = v;
  }
  __syncthreads();
  if (tid == 0) {
    float lg[E_];
    float mx = -1e30f;
    for (int o = 0; o < E_; ++o) {
      lg[o] = lred[o][0] + lred[o][1] + lred[o][2] + lred[o][3] + bo[o];
      mx = fmaxf(mx, lg[o]);
    }
    int i1 = 0;
    for (int o = 1; o < E_; ++o) if (lg[o] > lg[i1]) i1 = o;
    int i2 = (i1 == 0) ? 1 : 0;
    for (int o = 0; o < E_; ++o) if (o != i1 && lg[o] > lg[i2]) i2 = o;
    float p[E_], sum = 0.0f;
    for (int o = 0; o < E_; ++o) { p[o] = __expf(lg[o] - mx); sum += p[o]; }
    const float p1 = p[i1] / sum, p2 = p[i2] / sum;
    const float den = p1 + p2 + 1e-9f;
    tidx[b * 2] = i1; tidx[b * 2 + 1] = i2;
    gates[b * 2] = p1 / den; gates[b * 2 + 1] = p2 / den;
  }
}

// ---------------------------------------------------------------------------
// Final: 3-way LayerNorm + gating + bf16 cast of combined; f32 output.
// ---------------------------------------------------------------------------
__global__ __launch_bounds__(256)
void final_ln_k(float* __restrict__ outp, const ushort_t* __restrict__ so,
                const float* __restrict__ gates, const int* __restrict__ tidx,
                const float* __restrict__ e_gam, const float* __restrict__ e_bet,
                const float* __restrict__ g_gam, const float* __restrict__ g_bet) {
  const int row = blockIdx.x;
  const int b = row >> 9, l = row & 511;
  const int tid = threadIdx.x;
  __shared__ float red4[4];
  float* gr = outp + (size_t)row * D_;
  const ushort_t* s0 = so + (((size_t)b * 2 + 0) * L_ + l) * D_;
  const ushort_t* s1 = so + (((size_t)b * 2 + 1) * L_ + l) * D_;
  float a0[3], a1[3], a2[3];
#pragma unroll
  for (int j = 0; j < 3; ++j) {
    const int d = tid + j * 256;
    a0[j] = gr[d];
    a1[j] = bf2f(s0[d]);
    a2[j] = bf2f(s1[d]);
  }
  auto bsum = [&](float v) -> float {
#pragma unroll
    for (int o = 32; o > 0; o >>= 1) v += __shfl_down(v, o, 64);
    if ((tid & 63) == 0) red4[tid >> 6] = v;
    __syncthreads();
    const float r = red4[0] + red4[1] + red4[2] + red4[3];
    __syncthreads();
    return r;
  };
  const float sg = bsum(a0[0] + a0[1] + a0[2]);
  const float qg = bsum(a0[0] * a0[0] + a0[1] * a0[1] + a0[2] * a0[2]);
  const float s0s = bsum(a1[0] + a1[1] + a1[2]);
  const float q0s = bsum(a1[0] * a1[0] + a1[1] * a1[1] + a1[2] * a1[2]);
  const float s1s = bsum(a2[0] + a2[1] + a2[2]);
  const float q1s = bsum(a2[0] * a2[0] + a2[1] * a2[1] + a2[2] * a2[2]);
  const float inv = 1.0f / 768.0f;
  const float mug = sg * inv, rg = rsqrtf(qg * inv - mug * mug + 1e-5f);
  const float mu0 = s0s * inv, r0 = rsqrtf(q0s * inv - mu0 * mu0 + 1e-5f);
  const float mu1 = s1s * inv, r1 = rsqrtf(q1s * inv - mu1 * mu1 + 1e-5f);
  const int e0 = tidx[b * 2], e1 = tidx[b * 2 + 1];
  const float g0 = gates[b * 2], g1 = gates[b * 2 + 1];
#pragma unroll
  for (int j = 0; j < 3; ++j) {
    const int d = tid + j * 256;
    const float lng = (a0[j] - mug) * rg * g_gam[d] + g_bet[d];
    const float ln0 = (a1[j] - mu0) * r0 * e_gam[(size_t)e0 * D_ + d] + e_bet[(size_t)e0 * D_ + d];
    const float ln1 = (a2[j] - mu1) * r1 * e_gam[(size_t)e1 * D_ + d] + e_bet[(size_t)e1 * D_ + d];
    const float comb = g0 * ln0 + g1 * ln1;
    gr[d] = lng + bf2f(f2bf(comb));
  }
}

// ---------------------------------------------------------------------------
extern "C" void kernel_launch(void* const* d_in, const int* in_sizes, int n_in,
                              void* d_out, int out_size, void* d_ws, size_t ws_size,
                              hipStream_t stream) {
  const float* x_f  = (const float*)d_in[0];
  const float* cyc  = (const float*)d_in[1];
  const float* emb  = (const float*)d_in[2];
  const float* We   = (const float*)d_in[3];
  const float* Wc   = (const float*)d_in[4];
  const float* gb   = (const float*)d_in[5];
  const float* Wo   = (const float*)d_in[6];
  const float* bo   = (const float*)d_in[7];
  const float* e_w1 = (const float*)d_in[8];
  const float* e_b1 = (const float*)d_in[9];
  const float* e_w2 = (const float*)d_in[10];
  const float* e_b2 = (const float*)d_in[11];
  const float* e_gam = (const float*)d_in[12];
  const float* e_bet = (const float*)d_in[13];
  const float* g_w1 = (const float*)d_in[14];
  const float* g_b1 = (const float*)d_in[15];
  const float* g_w2 = (const float*)d_in[16];
  const float* g_b2 = (const float*)d_in[17];
  const float* g_gam = (const float*)d_in[18];
  const float* g_bet = (const float*)d_in[19];
  float* outp = (float*)d_out;
  char* ws = (char*)d_ws;

  size_t off = 0;
  auto alloc = [&](size_t bytes) { size_t o = off; off = (off + bytes + 255) & ~(size_t)255; return o; };
  const size_t o_idx  = alloc(32 * 4);
  const size_t o_gate = alloc(32 * 4);
  const size_t o_rp   = alloc((size_t)16 * B_ * DFF_ * 4);
  const size_t o_xb   = alloc((size_t)B_ * L_ * D_ * 2);
  const size_t o_w1t  = alloc((size_t)9 * DFF_ * D_ * 2);
  const size_t o_w2t  = alloc((size_t)9 * D_ * DFF_ * 2);
  const size_t o_so   = alloc((size_t)B_ * 2 * L_ * D_ * 2);
  const size_t o_h    = off;

  int JP = 1;
  const int divs[10] = {48, 24, 16, 12, 8, 6, 4, 3, 2, 1};
  for (int k = 0; k < 10; ++k) {
    if (o_h + (size_t)divs[k] * L_ * DFF_ * 2 <= ws_size) { JP = divs[k]; break; }
  }

  ushort_t* xb    = (ushort_t*)(ws + o_xb);
  ushort_t* w1t   = (ushort_t*)(ws + o_w1t);
  ushort_t* w2t   = (ushort_t*)(ws + o_w2t);
  ushort_t* so    = (ushort_t*)(ws + o_so);
  ushort_t* h_ws  = (ushort_t*)(ws + o_h);
  int*      tidx  = (int*)(ws + o_idx);
  float*    gates = (float*)(ws + o_gate);
  float*    rp    = (float*)(ws + o_rp);

  cvt_x_k<<<dim3((B_ * L_ * D_) / 1024), dim3(256), 0, stream>>>(x_f, xb);
  transpose_cvt_k<<<dim3(DFF_ / 64, D_ / 64, 9), dim3(256), 0, stream>>>(e_w1, g_w1, w1t, D_, DFF_);
  transpose_cvt_k<<<dim3(D_ / 64, DFF_ / 64, 9), dim3(256), 0, stream>>>(e_w2, g_w2, w2t, DFF_, D_);
  router_partial_k<<<dim3(12, 16), dim3(256), 0, stream>>>(emb, We, rp);
  router_final_k<<<dim3(16), dim3(256), 0, stream>>>(rp, cyc, Wc, gb, Wo, bo, tidx, gates);

  const int passes = 48 / JP;
  for (int p = 0; p < passes; ++p) {
    gemm1_k<<<dim3(64 * JP), dim3(256), 0, stream>>>(xb, w1t, e_b1, g_b1, tidx, h_ws, p * JP, JP);
    gemm2_k<<<dim3(16 * JP), dim3(256), 0, stream>>>(h_ws, w2t, e_b2, g_b2, x_f, tidx, so, outp, p * JP, JP);
  }
  final_ln_k<<<dim3(B_ * L_), dim3(256), 0, stream>>>(outp, so, gates, tidx,
                                                      e_gam, e_bet, g_gam, g_bet);
}